// Round 10
// baseline (125.266 us; speedup 1.0000x reference)
//
#include <hip/hip_runtime.h>

// B=2, L=4096, D_IN=256, D_OUT=256, K=16
// out[b,l,p] = sum_k lam_k * sum_m ev[k,(l-m)%L] * (sum_d u[b,m,d]*M[k,d,p])
//
// Pipeline:
//   0) prep: Mt[k,p,d], ubT[b,d,l] bf16 transposes (192 wgs x4 tiles)
//            + 8 ev-pair FFTs -> Hbuf (f32 split spectrum)
//   1) fft_fwd: 256 u d-pair FFTs -> Ut bf16 split spectrum
//   2) gemm_spec: Chat = sum_k H_k * (Uhat . M_k)  -- 8 waves =
//      2 k-half x 2 d-half x 2 bin-grp; M staged via global_load_lds
//      (inverse-swizzled source, dbuf, 1 barrier/kh); 2-pass LDS reduce.
//   3) ifft_store -> ytmp;  4) tr_out -> out
//
// Spectrum rows f2: [0..2047]=Re(f), [2048]=Nyquist(real, in dead Im(0)),
// [2049..4095]=Im(f).   (verified r2/r3/r8/r9, absmax 4.0)

typedef unsigned int uint;
using u16x8 = __attribute__((ext_vector_type(8))) unsigned short;
using s16x8 = __attribute__((ext_vector_type(8))) short;
using f32x4 = __attribute__((ext_vector_type(4))) float;

__device__ __forceinline__ unsigned short f2bf(float f) {
  uint u = __float_as_uint(f);
  uint r = (u + 0x7FFF + ((u >> 16) & 1)) >> 16;   // RNE
  return (unsigned short)r;
}
__device__ __forceinline__ float bf2f(unsigned short h) {
  return __uint_as_float(((uint)h) << 16);
}

__device__ __forceinline__ void gload_lds16(const void* g, void* l) {
  __builtin_amdgcn_global_load_lds(
      (const __attribute__((address_space(1))) unsigned int*)g,
      (__attribute__((address_space(3))) unsigned int*)l, 16, 0, 0);
}

// ---------------------------------------------------------------------------
// Radix-4 Stockham DIF FFT, N=4096, 6 stages, autosort (verified r2..r9).
// ---------------------------------------------------------------------------
template <int NT>
__device__ __forceinline__ void fft4096(float2* __restrict__ a,
                                        float2* __restrict__ b,
                                        const float2* __restrict__ tw, int tid) {
  float2* src = a;
  float2* dst = b;
#pragma unroll
  for (int s = 0; s < 12; s += 2) {
    const int m = 1 << s;
#pragma unroll
    for (int it = 0; it < 1024 / NT; ++it) {
      int idx = tid + it * NT;
      int i   = idx & (m - 1);
      int jm  = idx - i;
      float2 A0 = src[idx];
      float2 B0 = src[idx + 1024];
      float2 C0 = src[idx + 2048];
      float2 D0 = src[idx + 3072];
      float2 w1 = tw[jm];
      float2 w2 = make_float2(w1.x * w1.x - w1.y * w1.y, 2.f * w1.x * w1.y);
      float2 w3 = make_float2(w2.x * w1.x - w2.y * w1.y, w2.x * w1.y + w2.y * w1.x);
      float acx = A0.x + C0.x, acy = A0.y + C0.y;
      float amx = A0.x - C0.x, amy = A0.y - C0.y;
      float bdx = B0.x + D0.x, bdy = B0.y + D0.y;
      float bmx = B0.x - D0.x, bmy = B0.y - D0.y;
      float2 y0 = make_float2(acx + bdx, acy + bdy);
      float2 t2 = make_float2(acx - bdx, acy - bdy);
      float2 t1 = make_float2(amx + bmy, amy - bmx);
      float2 t3 = make_float2(amx - bmy, amy + bmx);
      int base = idx + 3 * jm;
      dst[base]         = y0;
      dst[base + m]     = make_float2(w1.x * t1.x - w1.y * t1.y, w1.x * t1.y + w1.y * t1.x);
      dst[base + 2 * m] = make_float2(w2.x * t2.x - w2.y * t2.y, w2.x * t2.y + w2.y * t2.x);
      dst[base + 3 * m] = make_float2(w3.x * t3.x - w3.y * t3.y, w3.x * t3.y + w3.y * t3.x);
    }
    __syncthreads();
    float2* t = src; src = dst; dst = t;
  }
}

template <int NT>
__device__ __forceinline__ void build_tw(float2* tw, int tid) {
  for (int t = tid; t < 1024; t += NT) {
    float ang = -(float)t * (6.283185307179586f / 4096.0f);
    float s, c;
    sincosf(ang, &s, &c);
    tw[t] = make_float2(c, s);
  }
}

// ---------------------------------------------------------------------------
// prep: bid<192: four 64x64 transpose tiles (M->Mt, u->ubT, verified bodies)
//       bid>=192: one ev-PAIR FFT -> Hbuf rows 2j,2j+1 (f32 split spectrum)
// 1024 threads; shared = union(4x t[64][65] f32 = 66560B, FFT 73728B)
// ---------------------------------------------------------------------------
__global__ __launch_bounds__(1024) void prep(const float* __restrict__ M,
                                             const float* __restrict__ u,
                                             const float* __restrict__ ev,
                                             const float* __restrict__ lam,
                                             unsigned short* __restrict__ Mt,
                                             unsigned short* __restrict__ ubT,
                                             float* __restrict__ Hbuf) {
  __shared__ float smem[18432];           // 73728 bytes
  const int bid = blockIdx.x;
  const int tid = threadIdx.x;

  if (bid < 192) {
    const int sub  = tid >> 8;            // 4 tiles per block
    const int t256 = tid & 255;
    const int tile = bid * 4 + sub;       // 0..767
    float (*t)[65] = (float(*)[65])(smem + sub * 4160);
    const int r = t256 >> 2, c0 = (t256 & 3) * 16;
    const float* src;
    unsigned short* dst;
    if (tile < 256) {                     // M tile
      const int k = tile >> 4, d0 = ((tile >> 2) & 3) * 64, pp = (tile & 3) * 64;
      src = M + ((size_t)k * 256 + d0) * 256 + pp;
      dst = Mt + ((size_t)k * 256 + pp + r) * 256 + d0 + c0;
    } else {                              // u tile
      const int b2 = tile - 256;
      const int l0 = (b2 & 63) * 64, d0 = ((b2 >> 6) & 3) * 64, plane = b2 >> 8;
      src = u + ((size_t)plane * 4096 + l0) * 256 + d0;
      dst = ubT + ((size_t)plane * 256 + d0 + r) * 4096 + l0 + c0;
    }
#pragma unroll
    for (int j = 0; j < 4; ++j) {
      float4 v = *(const float4*)(src + (size_t)r * 256 + c0 + j * 4);
      t[r][c0 + j * 4 + 0] = v.x;
      t[r][c0 + j * 4 + 1] = v.y;
      t[r][c0 + j * 4 + 2] = v.z;
      t[r][c0 + j * 4 + 3] = v.w;
    }
    __syncthreads();
    u16x8 o0, o1;
#pragma unroll
    for (int j = 0; j < 8; ++j) o0[j] = f2bf(t[c0 + j][r]);
#pragma unroll
    for (int j = 0; j < 8; ++j) o1[j] = f2bf(t[c0 + 8 + j][r]);
    *(u16x8*)dst = o0;
    *(u16x8*)(dst + 8) = o1;
  } else {
    // ev-pair FFT: z = ev[2j] + i*ev[2j+1]
    float2* A  = (float2*)smem;           // 4096 float2
    float2* Bb = (float2*)(smem + 8192);
    float2* tw = (float2*)(smem + 16384);
    build_tw<1024>(tw, tid);
    const int k0 = (bid - 192) * 2;
    const float* e0 = ev + (size_t)k0 * 4096;
    const float* e1 = e0 + 4096;
#pragma unroll
    for (int i = 0; i < 4; ++i) {
      int l = tid + i * 1024;
      A[l] = make_float2(e0[l], e1[l]);
    }
    __syncthreads();
    fft4096<1024>(A, Bb, tw, tid);
    const float s0 = lam[k0] * (1.0f / 4096.0f);
    const float s1 = lam[k0 + 1] * (1.0f / 4096.0f);
    float* H0 = Hbuf + (size_t)k0 * 4096;
    float* H1 = H0 + 4096;
#pragma unroll
    for (int i = 0; i < 2; ++i) {
      int f = tid + i * 1024;             // 0..2047
      float e0x, e0y, e1x, e1y;
      if (f == 0) {
        float2 X0 = A[0], Xn = A[2048];
        e0x = X0.x; e1x = X0.y;           // DC (real)
        e0y = Xn.x; e1y = Xn.y;           // Nyquist -> im-slot 0
      } else {
        float2 Xa = A[f], Xb = A[4096 - f];
        e0x = 0.5f * (Xa.x + Xb.x);
        e0y = 0.5f * (Xa.y - Xb.y);
        e1x = 0.5f * (Xa.y + Xb.y);
        e1y = 0.5f * (Xb.x - Xa.x);
      }
      H0[f] = s0 * e0x; H0[2048 + f] = s0 * e0y;
      H1[f] = s1 * e1x; H1[2048 + f] = s1 * e1y;
    }
  }
}

// ---------------------------------------------------------------------------
// Forward FFTs: exactly 256 wgs (one round), u d-pairs only, XCD-grouped.
// ---------------------------------------------------------------------------
__global__ __launch_bounds__(1024) void fft_fwd(const unsigned short* __restrict__ ubT,
                                                unsigned short* __restrict__ Ut) {
  __shared__ float2 A[4096];
  __shared__ float2 Bb[4096];
  __shared__ float2 tw[1024];
  const int tid = threadIdx.x;
  const int bid = blockIdx.x;
  build_tw<1024>(tw, tid);

  const int plane = bid >> 7;
  const int jj = bid & 127;
  const int pair = (jj & 7) * 16 + (jj >> 3);     // XCD x -> pairs 16x..16x+15
  const int d0 = pair * 2;
  const unsigned short* r0 = ubT + ((size_t)plane * 256 + d0) * 4096;
  const unsigned short* r1 = r0 + 4096;
  const int l0 = tid * 4;
  ushort4 a4 = *(const ushort4*)(r0 + l0);
  ushort4 b4 = *(const ushort4*)(r1 + l0);
  A[l0 + 0] = make_float2(bf2f(a4.x), bf2f(b4.x));
  A[l0 + 1] = make_float2(bf2f(a4.y), bf2f(b4.y));
  A[l0 + 2] = make_float2(bf2f(a4.z), bf2f(b4.z));
  A[l0 + 3] = make_float2(bf2f(a4.w), bf2f(b4.w));
  __syncthreads();
  fft4096<1024>(A, Bb, tw, tid);
  unsigned short* Up = Ut + (size_t)plane * 4096 * 256 + d0;
#pragma unroll
  for (int i = 0; i < 2; ++i) {
    int f = tid + i * 1024;                       // 0..2047
    float u0x, u0y, u1x, u1y;
    if (f == 0) {
      float2 X0 = A[0], Xn = A[2048];
      u0x = X0.x; u1x = X0.y;                     // DC (real)
      u0y = Xn.x; u1y = Xn.y;                     // Nyquist -> im-slot 0
    } else {
      float2 Xa = A[f], Xb = A[4096 - f];
      u0x = 0.5f * (Xa.x + Xb.x);
      u0y = 0.5f * (Xa.y - Xb.y);
      u1x = 0.5f * (Xa.y + Xb.y);
      u1y = 0.5f * (Xb.x - Xa.x);
    }
    ushort2 re = make_ushort2(f2bf(u0x), f2bf(u1x));
    ushort2 im = make_ushort2(f2bf(u0y), f2bf(u1y));
    *(ushort2*)(Up + (size_t)f * 256)          = re;
    *(ushort2*)(Up + (size_t)(2048 + f) * 256) = im;
  }
}

// ---------------------------------------------------------------------------
// Spectral GEMM.  512 threads = 8 waves: wave = half*4 + dh*2 + bg.
//   half: k 0-7 / 8-15;  dh: d 0-127 / 128-255;  bg: bins bg*32..+31.
// U-fragments (k-indep) in regs: ure/uim[bf][kk] (bf<2 bin-frags, kk<4).
// M staged by global_load_lds, inverse-swizzled source, double-buffered,
// ONE __syncthreads per kh (compiler drains vmcnt at barrier).
// Epilogue: 2-pass LDS reduction over the 4 (half,dh) partials per bg.
// LDS: Ms[2 buf][2 half][64*256 bf16] = 128K + Hlds 8K.
// ---------------------------------------------------------------------------
__global__ __launch_bounds__(512) void gemm_spec(const unsigned short* __restrict__ Ut,
                                                 const unsigned short* __restrict__ Mt,
                                                 const float* __restrict__ Hbuf,
                                                 float* __restrict__ Chat) {
  __shared__ unsigned short Ms[2][2][64 * 256];
  __shared__ float Hlds[16 * 128];
  const int gi  = blockIdx.x;
  const int xcd = gi & 7;
  const int gj  = gi >> 3;
  const int fb    = (xcd * 4 + (gj & 3)) * 64;
  const int p0    = ((gj >> 2) & 3) * 64;
  const int plane = gj >> 4;

  const int tid  = threadIdx.x;
  const int lane = tid & 63;
  const int wave = tid >> 6;
  const int half = wave >> 2;
  const int dh   = (wave >> 1) & 1;
  const int bg   = wave & 1;
  const int w4   = wave & 3;                // wave index within its half

  // stage H for this f-tile: Hlds[k*128 + part*64 + j]
#pragma unroll
  for (int it = 0; it < 4; ++it) {
    int i2 = tid + it * 512;
    int k = i2 >> 7, rem = i2 & 127;
    Hlds[i2] = Hbuf[(size_t)k * 4096 + (rem >> 6) * 2048 + fb + (rem & 63)];
  }

  // U fragments -> regs (k-independent). bf-th bin-frag, kk-th d-slice.
  const unsigned short* Up = Ut + (size_t)plane * 4096 * 256;
  const int dly = (lane >> 4) * 8;
  s16x8 ure[2][4], uim[2][4];
#pragma unroll
  for (int bf = 0; bf < 2; ++bf) {
    int row = fb + bg * 32 + bf * 16 + (lane & 15);
#pragma unroll
    for (int kk = 0; kk < 4; ++kk) {
      int dcol = dh * 128 + kk * 32 + dly;
      ure[bf][kk] = *(const s16x8*)(Up + (size_t)row * 256 + dcol);
      uim[bf][kk] = *(const s16x8*)(Up + (size_t)(2048 + row) * 256 + dcol);
    }
  }

  // per-lane inverse-swizzled source offsets for M staging (loop-invariant):
  // this wave stages LDS bytes [w4*8192 + c*1024 + lane*16] of Ms[buf][half];
  // content(row,slot) must be Mt[k][p0+row][(slot^(row&7)) low-3-XOR].
  int srcoff[8];
#pragma unroll
  for (int c = 0; c < 8; ++c) {
    int b = w4 * 8192 + c * 1024 + lane * 16;
    int row = b >> 9, slot = (b >> 4) & 31;
    int slot2 = (slot & ~7) | ((slot ^ (row & 7)) & 7);
    srcoff[c] = row * 512 + slot2 * 16;
  }
  const char* Mhalf = (const char*)Mt + (size_t)(half * 8) * 131072 + (size_t)p0 * 512;

  f32x4 cre[4][2], cim[4][2];
#pragma unroll
  for (int m = 0; m < 4; ++m)
#pragma unroll
    for (int bf = 0; bf < 2; ++bf) {
      cre[m][bf] = (f32x4){0.f, 0.f, 0.f, 0.f};
      cim[m][bf] = (f32x4){0.f, 0.f, 0.f, 0.f};
    }

  // prologue: stage k0 into buf 0
  {
    const char* src = Mhalf;
#pragma unroll
    for (int c = 0; c < 8; ++c)
      gload_lds16(src + srcoff[c], &Ms[0][half][w4 * 4096 + c * 512]);
  }
  __syncthreads();                          // drains vmcnt before barrier

  int cur = 0;
  for (int kh = 0; kh < 8; ++kh) {
    if (kh < 7) {                           // prefetch next k into other buf
      const char* src = Mhalf + (size_t)(kh + 1) * 131072;
#pragma unroll
      for (int c = 0; c < 8; ++c)
        gload_lds16(src + srcoff[c], &Ms[cur ^ 1][half][w4 * 4096 + c * 512]);
    }

    f32x4 are[4][2], aim[4][2];
#pragma unroll
    for (int m = 0; m < 4; ++m)
#pragma unroll
      for (int bf = 0; bf < 2; ++bf) {
        are[m][bf] = (f32x4){0.f, 0.f, 0.f, 0.f};
        aim[m][bf] = (f32x4){0.f, 0.f, 0.f, 0.f};
      }
#pragma unroll
    for (int kk = 0; kk < 4; ++kk) {
      const int kc = dh * 16 + kk * 4 + (lane >> 4);
#pragma unroll
      for (int m = 0; m < 4; ++m) {
        int row = m * 16 + (lane & 15);
        s16x8 af = *(const s16x8*)(&Ms[cur][half][row * 256 + ((kc ^ (row & 7)) * 8)]);
        are[m][0] = __builtin_amdgcn_mfma_f32_16x16x32_bf16(af, ure[0][kk], are[m][0], 0, 0, 0);
        aim[m][0] = __builtin_amdgcn_mfma_f32_16x16x32_bf16(af, uim[0][kk], aim[m][0], 0, 0, 0);
        are[m][1] = __builtin_amdgcn_mfma_f32_16x16x32_bf16(af, ure[1][kk], are[m][1], 0, 0, 0);
        aim[m][1] = __builtin_amdgcn_mfma_f32_16x16x32_bf16(af, uim[1][kk], aim[m][1], 0, 0, 0);
      }
    }
    const int k = kh + 8 * half;
#pragma unroll
    for (int bf = 0; bf < 2; ++bf) {
      int boff = bg * 32 + bf * 16 + (lane & 15);
      float hre = Hlds[k * 128 + boff];
      float hs  = Hlds[k * 128 + 64 + boff];
      bool sp = (fb + boff == 0);           // im slot holds Nyquist at bin 0
      float him = sp ? 0.0f : hs;
      float hA  = sp ? hs : hre;
#pragma unroll
      for (int m = 0; m < 4; ++m)
#pragma unroll
        for (int i = 0; i < 4; ++i) {
          cre[m][bf][i] += hre * are[m][bf][i] - him * aim[m][bf][i];
          cim[m][bf][i] += hA * aim[m][bf][i] + him * are[m][bf][i];
        }
    }
    __syncthreads();                        // all reads of cur done; prefetch landed
    cur ^= 1;
  }

  // 2-pass reduction over the 4 (half,dh) partials; result in waves 0,1 (bg).
  float* Red = (float*)Ms;                  // 64 KB scratch per pass
#pragma unroll
  for (int m = 0; m < 4; ++m)
#pragma unroll
    for (int bf = 0; bf < 2; ++bf)
#pragma unroll
      for (int i = 0; i < 4; ++i)
        Red[((m * 2 + bf) * 4 + i) * 512 + tid] = cre[m][bf][i];
  __syncthreads();
  float rsum[32];
  if (tid < 128) {
#pragma unroll
    for (int s = 0; s < 32; ++s)
      rsum[s] = Red[s * 512 + tid] + Red[s * 512 + tid + 128] +
                Red[s * 512 + tid + 256] + Red[s * 512 + tid + 384];
  }
  __syncthreads();
#pragma unroll
  for (int m = 0; m < 4; ++m)
#pragma unroll
    for (int bf = 0; bf < 2; ++bf)
#pragma unroll
      for (int i = 0; i < 4; ++i)
        Red[((m * 2 + bf) * 4 + i) * 512 + tid] = cim[m][bf][i];
  __syncthreads();
  if (tid < 128) {
    const int ln  = tid & 63;
    const int bgs = tid >> 6;
    float* Cp = Chat + ((size_t)plane * 256 + p0) * 4096;
#pragma unroll
    for (int m = 0; m < 4; ++m)
#pragma unroll
      for (int bf = 0; bf < 2; ++bf) {
        int bin = fb + bgs * 32 + bf * 16 + (ln & 15);
#pragma unroll
        for (int i = 0; i < 4; ++i) {
          int s = (m * 2 + bf) * 4 + i;
          int pl = m * 16 + (ln >> 4) * 4 + i;
          float isum = Red[s * 512 + tid] + Red[s * 512 + tid + 128] +
                       Red[s * 512 + tid + 256] + Red[s * 512 + tid + 384];
          Cp[(size_t)pl * 4096 + bin]        = rsum[s];
          Cp[(size_t)pl * 4096 + 2048 + bin] = isum;
        }
      }
  }
}

// ---------------------------------------------------------------------------
// Inverse: rebuild Hermitian spectra per p-pair, y = FFT(conj(C));
// write ytmp[plane][p][l] contiguously.
// ---------------------------------------------------------------------------
__global__ __launch_bounds__(1024) void ifft_store(const float* __restrict__ Chat,
                                                   float* __restrict__ ytmp) {
  __shared__ float2 A[4096];
  __shared__ float2 Bb[4096];
  __shared__ float2 tw[1024];
  const int tid = threadIdx.x;
  const int p0 = blockIdx.x * 2;
  const int plane = blockIdx.y;
  const float* C0 = Chat + ((size_t)plane * 256 + p0) * 4096;
  const float* C1 = C0 + 4096;
  build_tw<1024>(tw, tid);

  if (tid == 0) {
    A[0]    = make_float2(C0[0], -C1[0]);          // DC (real)
    A[2048] = make_float2(C0[2048], -C1[2048]);    // Nyquist (real)
  } else {
    int f = tid;                                   // 1..1023
    float cr0 = C0[f], ci0 = C0[2048 + f];
    float cr1 = C1[f], ci1 = C1[2048 + f];
    A[f]        = make_float2(cr0 - ci1, -(ci0 + cr1));
    A[4096 - f] = make_float2(cr0 + ci1, ci0 - cr1);
  }
  {
    int f = tid + 1024;                            // 1024..2047
    float cr0 = C0[f], ci0 = C0[2048 + f];
    float cr1 = C1[f], ci1 = C1[2048 + f];
    A[f]        = make_float2(cr0 - ci1, -(ci0 + cr1));
    A[4096 - f] = make_float2(cr0 + ci1, ci0 - cr1);
  }
  __syncthreads();
  fft4096<1024>(A, Bb, tw, tid);

  float* y0 = ytmp + ((size_t)plane * 256 + p0) * 4096;
  float* y1 = y0 + 4096;
#pragma unroll
  for (int i = 0; i < 4; ++i) {
    int l = tid + i * 1024;
    float2 g = A[l];
    y0[l] = g.x;
    y1[l] = -g.y;
  }
}

// ---------------------------------------------------------------------------
// ytmp[plane][p][l] -> out[plane][l][p]   (64x64 f32 tiles, coalesced)
// ---------------------------------------------------------------------------
__global__ __launch_bounds__(256) void tr_out(const float* __restrict__ ytmp,
                                              float* __restrict__ out) {
  __shared__ float t[64][65];
  const int l0 = blockIdx.x * 64, p0 = blockIdx.y * 64, plane = blockIdx.z;
  const int r = threadIdx.x >> 2, c0 = (threadIdx.x & 3) * 16;
  const float* src = ytmp + ((size_t)plane * 256 + p0 + r) * 4096 + l0;
#pragma unroll
  for (int j = 0; j < 4; ++j) {
    float4 v = *(const float4*)(src + c0 + j * 4);
    t[r][c0 + j * 4 + 0] = v.x;
    t[r][c0 + j * 4 + 1] = v.y;
    t[r][c0 + j * 4 + 2] = v.z;
    t[r][c0 + j * 4 + 3] = v.w;
  }
  __syncthreads();
  float* dst = out + ((size_t)plane * 4096 + l0 + r) * 256 + p0 + c0;
#pragma unroll
  for (int q = 0; q < 4; ++q) {
    float4 o;
    o.x = t[c0 + q * 4 + 0][r];
    o.y = t[c0 + q * 4 + 1][r];
    o.z = t[c0 + q * 4 + 2][r];
    o.w = t[c0 + q * 4 + 3][r];
    *(float4*)(dst + q * 4) = o;
  }
}

// ---------------------------------------------------------------------------
extern "C" void kernel_launch(void* const* d_in, const int* in_sizes, int n_in,
                              void* d_out, int out_size, void* d_ws,
                              size_t ws_size, hipStream_t stream) {
  const float* u   = (const float*)d_in[0];  // (2, 4096, 256)
  const float* ev  = (const float*)d_in[1];  // (16, 4096)
  const float* lam = (const float*)d_in[2];  // (16,)
  const float* M   = (const float*)d_in[3];  // (16, 256, 256)
  float* out = (float*)d_out;                // (2, 4096, 256)

  char* ws = (char*)d_ws;
  float* Hbuf         = (float*)ws;                          // 256 KB
  unsigned short* Mt  = (unsigned short*)(ws + (256 << 10)); // 2 MB
  unsigned short* ubT = (unsigned short*)(ws + (256 << 10) + (2 << 20));  // 4 MB
  unsigned short* Ut  = (unsigned short*)(ws + (256 << 10) + (6 << 20));  // 4 MB
  float* Chat         = (float*)(ws + (256 << 10) + (10 << 20));          // 8 MB
  float* ytmp         = (float*)(ws + (256 << 10) + (18 << 20));          // 8 MB

  prep<<<200, 1024, 0, stream>>>(M, u, ev, lam, Mt, ubT, Hbuf);
  fft_fwd<<<256, 1024, 0, stream>>>(ubT, Ut);
  gemm_spec<<<256, 512, 0, stream>>>(Ut, Mt, Hbuf, Chat);
  ifft_store<<<dim3(128, 2), 1024, 0, stream>>>(Chat, ytmp);
  tr_out<<<dim3(64, 4, 2), 256, 0, stream>>>(ytmp, out);
}

// Round 11
// 116.960 us; speedup vs baseline: 1.0710x; 1.0710x over previous
//
#include <hip/hip_runtime.h>

// B=2, L=4096, D_IN=256, D_OUT=256, K=16
// out[b,l,p] = sum_k lam_k * sum_m ev[k,(l-m)%L] * (sum_d u[b,m,d]*M[k,d,p])
//
// Frequency-domain-first pipeline (round-9 verified configuration):
//   0) prep: ubT[b,d,l] = bf16 transpose of u;  Mt[k,p,d] = bf16 transpose of M
//   1) Uhat[b,f2,d] = FFT_l(ubT)   (256 packed d-pair FFTs + 16 ev FFTs)
//   2) Chat[b,p,f2] = sum_k H[k,f] * sum_d Uhat[f,d]*Mt[k,p,d]   (MFMA,
//      512-thr blocks, k split across wave-halves; U-fragments held in
//      REGISTERS across the k-loop (k-independent); LDS reduction at end)
//   3) ytmp[b,p,l] = IFFT_f(Chat);  4) out[b,l,p] = transpose(ytmp)
//
// Spectrum rows f2: [0..2047]=Re(f), [2048]=Nyquist(real, in dead Im(0)),
// [2049..4095]=Im(f).   (verified rounds 2-3/8/9, absmax 4.0)

typedef unsigned int uint;
using u16x8 = __attribute__((ext_vector_type(8))) unsigned short;
using s16x8 = __attribute__((ext_vector_type(8))) short;
using f32x4 = __attribute__((ext_vector_type(4))) float;

__device__ __forceinline__ unsigned short f2bf(float f) {
  uint u = __float_as_uint(f);
  uint r = (u + 0x7FFF + ((u >> 16) & 1)) >> 16;   // RNE
  return (unsigned short)r;
}
__device__ __forceinline__ float bf2f(unsigned short h) {
  return __uint_as_float(((uint)h) << 16);
}

// ---------------------------------------------------------------------------
// Radix-4 Stockham DIF FFT, N=4096, 6 stages, autosort (verified r2/r3/r8/r9).
// ---------------------------------------------------------------------------
template <int NT>
__device__ __forceinline__ void fft4096(float2* __restrict__ a,
                                        float2* __restrict__ b,
                                        const float2* __restrict__ tw, int tid) {
  float2* src = a;
  float2* dst = b;
#pragma unroll
  for (int s = 0; s < 12; s += 2) {
    const int m = 1 << s;
#pragma unroll
    for (int it = 0; it < 1024 / NT; ++it) {
      int idx = tid + it * NT;
      int i   = idx & (m - 1);
      int jm  = idx - i;
      float2 A0 = src[idx];
      float2 B0 = src[idx + 1024];
      float2 C0 = src[idx + 2048];
      float2 D0 = src[idx + 3072];
      float2 w1 = tw[jm];
      float2 w2 = make_float2(w1.x * w1.x - w1.y * w1.y, 2.f * w1.x * w1.y);
      float2 w3 = make_float2(w2.x * w1.x - w2.y * w1.y, w2.x * w1.y + w2.y * w1.x);
      float acx = A0.x + C0.x, acy = A0.y + C0.y;
      float amx = A0.x - C0.x, amy = A0.y - C0.y;
      float bdx = B0.x + D0.x, bdy = B0.y + D0.y;
      float bmx = B0.x - D0.x, bmy = B0.y - D0.y;
      float2 y0 = make_float2(acx + bdx, acy + bdy);
      float2 t2 = make_float2(acx - bdx, acy - bdy);
      float2 t1 = make_float2(amx + bmy, amy - bmx);
      float2 t3 = make_float2(amx - bmy, amy + bmx);
      int base = idx + 3 * jm;
      dst[base]         = y0;
      dst[base + m]     = make_float2(w1.x * t1.x - w1.y * t1.y, w1.x * t1.y + w1.y * t1.x);
      dst[base + 2 * m] = make_float2(w2.x * t2.x - w2.y * t2.y, w2.x * t2.y + w2.y * t2.x);
      dst[base + 3 * m] = make_float2(w3.x * t3.x - w3.y * t3.y, w3.x * t3.y + w3.y * t3.x);
    }
    __syncthreads();
    float2* t = src; src = dst; dst = t;
  }
}

template <int NT>
__device__ __forceinline__ void build_tw(float2* tw, int tid) {
  for (int t = tid; t < 1024; t += NT) {
    float ang = -(float)t * (6.283185307179586f / 4096.0f);
    float s, c;
    sincosf(ang, &s, &c);
    tw[t] = make_float2(c, s);
  }
}

// ---------------------------------------------------------------------------
// prep: bid<256: M[k][d][p] f32 -> Mt[k][p][d] bf16 (64x64 tiles)
//       bid>=256: u[b][l][d] f32 -> ubT[b][d][l] bf16 (64x64 tiles)
// ---------------------------------------------------------------------------
__global__ __launch_bounds__(256) void prep(const float* __restrict__ M,
                                            const float* __restrict__ u,
                                            unsigned short* __restrict__ Mt,
                                            unsigned short* __restrict__ ubT) {
  __shared__ float t[64][65];
  const int bid = blockIdx.x;
  const int r = threadIdx.x >> 2, c0 = (threadIdx.x & 3) * 16;

  const float* src;
  unsigned short* dst;
  size_t src_stride;
  if (bid < 256) {                       // tr_M tile
    const int k = bid >> 4, d0 = ((bid >> 2) & 3) * 64, p0 = (bid & 3) * 64;
    src = M + ((size_t)k * 256 + d0) * 256 + p0;
    dst = Mt + ((size_t)k * 256 + p0 + r) * 256 + d0 + c0;
    src_stride = 256;
  } else {                               // tr_u tile
    const int b2 = bid - 256;
    const int l0 = (b2 & 63) * 64, d0 = ((b2 >> 6) & 3) * 64, plane = b2 >> 8;
    src = u + ((size_t)plane * 4096 + l0) * 256 + d0;
    dst = ubT + ((size_t)plane * 256 + d0 + r) * 4096 + l0 + c0;
    src_stride = 256;
  }
#pragma unroll
  for (int j = 0; j < 4; ++j) {
    float4 v = *(const float4*)(src + (size_t)r * src_stride + c0 + j * 4);
    t[r][c0 + j * 4 + 0] = v.x;
    t[r][c0 + j * 4 + 1] = v.y;
    t[r][c0 + j * 4 + 2] = v.z;
    t[r][c0 + j * 4 + 3] = v.w;
  }
  __syncthreads();
  u16x8 o0, o1;
#pragma unroll
  for (int j = 0; j < 8; ++j) o0[j] = f2bf(t[c0 + j][r]);
#pragma unroll
  for (int j = 0; j < 8; ++j) o1[j] = f2bf(t[c0 + 8 + j][r]);
  *(u16x8*)dst = o0;
  *(u16x8*)(dst + 8) = o1;
}

// ---------------------------------------------------------------------------
// Forward FFTs. bid<256: u d-pair (XCD-grouped so each Ut 64B line is written
// by one XCD). bid>=256: ev -> Hbuf.
// ---------------------------------------------------------------------------
__global__ __launch_bounds__(1024) void fft_fwd(const unsigned short* __restrict__ ubT,
                                                const float* __restrict__ ev,
                                                const float* __restrict__ lam,
                                                unsigned short* __restrict__ Ut,
                                                float* __restrict__ Hbuf) {
  __shared__ float2 A[4096];
  __shared__ float2 Bb[4096];
  __shared__ float2 tw[1024];
  const int tid = threadIdx.x;
  const int bid = blockIdx.x;
  build_tw<1024>(tw, tid);

  if (bid < 256) {
    const int plane = bid >> 7;
    const int jj = bid & 127;
    const int pair = (jj & 7) * 16 + (jj >> 3);   // XCD x -> pairs 16x..16x+15
    const int d0 = pair * 2;
    const unsigned short* r0 = ubT + ((size_t)plane * 256 + d0) * 4096;
    const unsigned short* r1 = r0 + 4096;
    const int l0 = tid * 4;
    ushort4 a4 = *(const ushort4*)(r0 + l0);
    ushort4 b4 = *(const ushort4*)(r1 + l0);
    A[l0 + 0] = make_float2(bf2f(a4.x), bf2f(b4.x));
    A[l0 + 1] = make_float2(bf2f(a4.y), bf2f(b4.y));
    A[l0 + 2] = make_float2(bf2f(a4.z), bf2f(b4.z));
    A[l0 + 3] = make_float2(bf2f(a4.w), bf2f(b4.w));
    __syncthreads();
    fft4096<1024>(A, Bb, tw, tid);
    unsigned short* Up = Ut + (size_t)plane * 4096 * 256 + d0;
#pragma unroll
    for (int i = 0; i < 2; ++i) {
      int f = tid + i * 1024;                     // 0..2047
      float u0x, u0y, u1x, u1y;
      if (f == 0) {
        float2 X0 = A[0], Xn = A[2048];
        u0x = X0.x; u1x = X0.y;                   // DC (real)
        u0y = Xn.x; u1y = Xn.y;                   // Nyquist -> im-slot 0
      } else {
        float2 Xa = A[f], Xb = A[4096 - f];
        u0x = 0.5f * (Xa.x + Xb.x);
        u0y = 0.5f * (Xa.y - Xb.y);
        u1x = 0.5f * (Xa.y + Xb.y);
        u1y = 0.5f * (Xb.x - Xa.x);
      }
      ushort2 re = make_ushort2(f2bf(u0x), f2bf(u1x));
      ushort2 im = make_ushort2(f2bf(u0y), f2bf(u1y));
      *(ushort2*)(Up + (size_t)f * 256)          = re;
      *(ushort2*)(Up + (size_t)(2048 + f) * 256) = im;
    }
  } else {
    const int k = bid - 256;
    const float* eb = ev + (size_t)k * 4096;
#pragma unroll
    for (int i = 0; i < 4; ++i) {
      int l = tid + i * 1024;
      A[l] = make_float2(eb[l], 0.0f);
    }
    __syncthreads();
    fft4096<1024>(A, Bb, tw, tid);
    const float sc = lam[k] * (1.0f / 4096.0f);
    float* Hp = Hbuf + (size_t)k * 4096;
#pragma unroll
    for (int i = 0; i < 2; ++i) {
      int f = tid + i * 1024;
      float2 X = A[f];
      Hp[f] = sc * X.x;
      Hp[2048 + f] = (f == 0) ? sc * A[2048].x : sc * X.y;
    }
  }
}

// ---------------------------------------------------------------------------
// Spectral GEMM + per-k complex filter accumulate.  512 threads, 8 waves.
// Waves 0-3: k=0..7; waves 4-7: k=8..15 (private Ms halves).
// U-fragments (k-INDEPENDENT) loaded once from global into 16 s16x8 regs:
//   frag kk, lane L: row = fb + w4*16 + (L&15) (+2048 for im),
//                    d = kk*32 + (L>>4)*8 .. +8
// End: LDS reduction of the two k-halves (scratch = Ms), waves 0-3 store.
// LDS: Ms 2x32K + Hlds 8K = 72K.
// ---------------------------------------------------------------------------
__global__ __launch_bounds__(512) void gemm_spec(const unsigned short* __restrict__ Ut,
                                                 const unsigned short* __restrict__ Mt,
                                                 const float* __restrict__ Hbuf,
                                                 float* __restrict__ Chat) {
  __shared__ unsigned short Ms[2][64 * 256];
  __shared__ float Hlds[16 * 128];
  // XCD-swizzled decode: each XCD gets 4 consecutive f-tiles x all p,plane
  const int gi  = blockIdx.x;
  const int xcd = gi & 7;
  const int gj  = gi >> 3;                  // 0..31
  const int fb    = (xcd * 4 + (gj & 3)) * 64;
  const int p0    = ((gj >> 2) & 3) * 64;
  const int plane = gj >> 4;

  const int tid  = threadIdx.x;
  const int lane = tid & 63;
  const int wave = tid >> 6;
  const int half = wave >> 2;               // k-half
  const int w4   = wave & 3;                // bin-group
  const int th   = tid & 255;

  // stage H for this f-tile: Hlds[k*128 + part*64 + j]
#pragma unroll
  for (int it = 0; it < 4; ++it) {
    int i2 = tid + it * 512;
    int k = i2 >> 7, rem = i2 & 127;
    Hlds[i2] = Hbuf[(size_t)k * 4096 + (rem >> 6) * 2048 + fb + (rem & 63)];
  }

  // U fragments -> registers (k-independent; held across the whole k-loop)
  const unsigned short* Up = Ut + (size_t)plane * 4096 * 256;
  const int binoff = w4 * 16 + (lane & 15);
  const int bin = fb + binoff;
  const int dly = (lane >> 4) * 8;
  s16x8 ure[8], uim[8];
#pragma unroll
  for (int kk = 0; kk < 8; ++kk) {
    ure[kk] = *(const s16x8*)(Up + (size_t)(fb + binoff) * 256 + kk * 32 + dly);
    uim[kk] = *(const s16x8*)(Up + (size_t)(2048 + fb + binoff) * 256 + kk * 32 + dly);
  }

  // prefetch M for this half's first k
  const unsigned short* Mbase = Mt + (size_t)half * 8 * 65536;
  u16x8 mreg[8];
#pragma unroll
  for (int it = 0; it < 8; ++it) {
    int cl = th + it * 256;
    int r = cl >> 5, c = cl & 31;
    mreg[it] = *(const u16x8*)(Mbase + (size_t)(p0 + r) * 256 + c * 8);
  }

  f32x4 cre[4], cim[4];
#pragma unroll
  for (int m = 0; m < 4; ++m) {
    cre[m] = (f32x4){0.f, 0.f, 0.f, 0.f};
    cim[m] = (f32x4){0.f, 0.f, 0.f, 0.f};
  }

  for (int kh = 0; kh < 8; ++kh) {
    if (kh > 0) __syncthreads();            // prev compute done with Ms
#pragma unroll
    for (int it = 0; it < 8; ++it) {
      int cl = th + it * 256;
      int r = cl >> 5, c = cl & 31;
      *(u16x8*)(&Ms[half][r * 256 + ((c ^ (r & 7)) * 8)]) = mreg[it];
    }
    if (kh < 7) {
      const unsigned short* Mk = Mbase + (size_t)(kh + 1) * 65536;
#pragma unroll
      for (int it = 0; it < 8; ++it) {
        int cl = th + it * 256;
        int r = cl >> 5, c = cl & 31;
        mreg[it] = *(const u16x8*)(Mk + (size_t)(p0 + r) * 256 + c * 8);
      }
    }
    __syncthreads();                        // Ms (and Hlds at kh=0) ready

    f32x4 are[4], aim[4];
#pragma unroll
    for (int m = 0; m < 4; ++m) {
      are[m] = (f32x4){0.f, 0.f, 0.f, 0.f};
      aim[m] = (f32x4){0.f, 0.f, 0.f, 0.f};
    }
#pragma unroll
    for (int kk = 0; kk < 8; ++kk) {
      const int kc = kk * 4 + (lane >> 4);
#pragma unroll
      for (int m = 0; m < 4; ++m) {
        int row = m * 16 + (lane & 15);
        s16x8 af = *(const s16x8*)(&Ms[half][row * 256 + ((kc ^ (row & 7)) * 8)]);
        are[m] = __builtin_amdgcn_mfma_f32_16x16x32_bf16(af, ure[kk], are[m], 0, 0, 0);
        aim[m] = __builtin_amdgcn_mfma_f32_16x16x32_bf16(af, uim[kk], aim[m], 0, 0, 0);
      }
    }
    const int k = kh + 8 * half;
    float hre = Hlds[k * 128 + binoff];
    float hs  = Hlds[k * 128 + 64 + binoff];
    bool sp = (bin == 0);                   // im slot holds Nyquist at bin 0
    float him = sp ? 0.0f : hs;
    float hA  = sp ? hs : hre;
#pragma unroll
    for (int m = 0; m < 4; ++m)
#pragma unroll
      for (int i = 0; i < 4; ++i) {
        cre[m][i] += hre * are[m][i] - him * aim[m][i];
        cim[m][i] += hA * aim[m][i] + him * are[m][i];
      }
  }

  // reduce the two k-halves via LDS (reuse Ms as 64KB float scratch)
  __syncthreads();
  float* Red = (float*)Ms;
#pragma unroll
  for (int m = 0; m < 4; ++m)
#pragma unroll
    for (int i = 0; i < 4; ++i) {
      Red[(m * 4 + i) * 512 + tid]        = cre[m][i];
      Red[(16 + m * 4 + i) * 512 + tid]   = cim[m][i];
    }
  __syncthreads();
  if (tid < 256) {
#pragma unroll
    for (int m = 0; m < 4; ++m)
#pragma unroll
      for (int i = 0; i < 4; ++i) {
        cre[m][i] += Red[(m * 4 + i) * 512 + tid + 256];
        cim[m][i] += Red[(16 + m * 4 + i) * 512 + tid + 256];
      }
    float* Cp = Chat + ((size_t)plane * 256 + p0) * 4096;
#pragma unroll
    for (int m = 0; m < 4; ++m)
#pragma unroll
      for (int i = 0; i < 4; ++i) {
        int pl = m * 16 + (lane >> 4) * 4 + i;
        Cp[(size_t)pl * 4096 + bin]        = cre[m][i];
        Cp[(size_t)pl * 4096 + 2048 + bin] = cim[m][i];
      }
  }
}

// ---------------------------------------------------------------------------
// Inverse: rebuild Hermitian spectra per p-pair, y = FFT(conj(C));
// write ytmp[plane][p][l] CONTIGUOUSLY (transpose to out happens after).
// ---------------------------------------------------------------------------
__global__ __launch_bounds__(1024) void ifft_store(const float* __restrict__ Chat,
                                                   float* __restrict__ ytmp) {
  __shared__ float2 A[4096];
  __shared__ float2 Bb[4096];
  __shared__ float2 tw[1024];
  const int tid = threadIdx.x;
  const int p0 = blockIdx.x * 2;
  const int plane = blockIdx.y;
  const float* C0 = Chat + ((size_t)plane * 256 + p0) * 4096;
  const float* C1 = C0 + 4096;
  build_tw<1024>(tw, tid);

  if (tid == 0) {
    A[0]    = make_float2(C0[0], -C1[0]);          // DC (real)
    A[2048] = make_float2(C0[2048], -C1[2048]);    // Nyquist (real)
  } else {
    int f = tid;                                   // 1..1023
    float cr0 = C0[f], ci0 = C0[2048 + f];
    float cr1 = C1[f], ci1 = C1[2048 + f];
    A[f]        = make_float2(cr0 - ci1, -(ci0 + cr1));
    A[4096 - f] = make_float2(cr0 + ci1, ci0 - cr1);
  }
  {
    int f = tid + 1024;                            // 1024..2047
    float cr0 = C0[f], ci0 = C0[2048 + f];
    float cr1 = C1[f], ci1 = C1[2048 + f];
    A[f]        = make_float2(cr0 - ci1, -(ci0 + cr1));
    A[4096 - f] = make_float2(cr0 + ci1, ci0 - cr1);
  }
  __syncthreads();
  fft4096<1024>(A, Bb, tw, tid);

  float* y0 = ytmp + ((size_t)plane * 256 + p0) * 4096;
  float* y1 = y0 + 4096;
#pragma unroll
  for (int i = 0; i < 4; ++i) {
    int l = tid + i * 1024;
    float2 g = A[l];
    y0[l] = g.x;
    y1[l] = -g.y;
  }
}

// ---------------------------------------------------------------------------
// ytmp[plane][p][l] -> out[plane][l][p]   (64x64 f32 tiles, coalesced)
// ---------------------------------------------------------------------------
__global__ __launch_bounds__(256) void tr_out(const float* __restrict__ ytmp,
                                              float* __restrict__ out) {
  __shared__ float t[64][65];
  const int l0 = blockIdx.x * 64, p0 = blockIdx.y * 64, plane = blockIdx.z;
  const int r = threadIdx.x >> 2, c0 = (threadIdx.x & 3) * 16;
  const float* src = ytmp + ((size_t)plane * 256 + p0 + r) * 4096 + l0;
#pragma unroll
  for (int j = 0; j < 4; ++j) {
    float4 v = *(const float4*)(src + c0 + j * 4);
    t[r][c0 + j * 4 + 0] = v.x;
    t[r][c0 + j * 4 + 1] = v.y;
    t[r][c0 + j * 4 + 2] = v.z;
    t[r][c0 + j * 4 + 3] = v.w;
  }
  __syncthreads();
  float* dst = out + ((size_t)plane * 4096 + l0 + r) * 256 + p0 + c0;
#pragma unroll
  for (int q = 0; q < 4; ++q) {
    float4 o;
    o.x = t[c0 + q * 4 + 0][r];
    o.y = t[c0 + q * 4 + 1][r];
    o.z = t[c0 + q * 4 + 2][r];
    o.w = t[c0 + q * 4 + 3][r];
    *(float4*)(dst + q * 4) = o;
  }
}

// ---------------------------------------------------------------------------
extern "C" void kernel_launch(void* const* d_in, const int* in_sizes, int n_in,
                              void* d_out, int out_size, void* d_ws,
                              size_t ws_size, hipStream_t stream) {
  const float* u   = (const float*)d_in[0];  // (2, 4096, 256)
  const float* ev  = (const float*)d_in[1];  // (16, 4096)
  const float* lam = (const float*)d_in[2];  // (16,)
  const float* M   = (const float*)d_in[3];  // (16, 256, 256)
  float* out = (float*)d_out;                // (2, 4096, 256)

  char* ws = (char*)d_ws;
  float* Hbuf         = (float*)ws;                          // 256 KB
  unsigned short* Mt  = (unsigned short*)(ws + (256 << 10)); // 2 MB
  unsigned short* ubT = (unsigned short*)(ws + (256 << 10) + (2 << 20));  // 4 MB
  unsigned short* Ut  = (unsigned short*)(ws + (256 << 10) + (6 << 20));  // 4 MB
  float* Chat         = (float*)(ws + (256 << 10) + (10 << 20));          // 8 MB
  float* ytmp         = (float*)(ws + (256 << 10) + (18 << 20));          // 8 MB

  prep<<<768, 256, 0, stream>>>(M, u, Mt, ubT);
  fft_fwd<<<272, 1024, 0, stream>>>(ubT, ev, lam, Ut, Hbuf);
  gemm_spec<<<256, 512, 0, stream>>>(Ut, Mt, Hbuf, Chat);
  ifft_store<<<dim3(128, 2), 1024, 0, stream>>>(Chat, ytmp);
  tr_out<<<dim3(64, 4, 2), 256, 0, stream>>>(ytmp, out);
}